// Round 10
// baseline (305.596 us; speedup 1.0000x reference)
//
#include <hip/hip_runtime.h>
#include <hip/hip_bf16.h>

typedef unsigned short u16;
typedef unsigned int u32;
typedef u16 u16x8 __attribute__((ext_vector_type(8)));
typedef __bf16 bf16x8 __attribute__((ext_vector_type(8)));
typedef float f32x4 __attribute__((ext_vector_type(4)));

#define B_SZ 2
#define T_SZ 2048
#define DMODEL 1024
#define DINNER 2048
#define DSTATE 128
#define NHEADS 32
#define HEADDIM 64
#define CONVDIM 2304
#define DINPROJ 4384
#define DINPROJ_P 4480        // padded to 35*128 for GEMM1 tiles
#define NROWS (B_SZ * T_SZ)   // 4096
#define L_CH 128
#define NCH 16                // chunks per batch (T/L)
#define BCW 256               // B+C packed width

__device__ __forceinline__ float bf2f(u16 u) {
    union { float f; u32 i; } v; v.i = ((u32)u) << 16; return v.f;
}
__device__ __forceinline__ u16 f2bf(float f) {
    union { float f; u32 i; } v; v.f = f;
    u32 r = v.i + 0x7FFFu + ((v.i >> 16) & 1u);
    return (u16)(r >> 16);
}
__device__ __forceinline__ bf16x8 ldfrag(const u16* p) {
    return __builtin_bit_cast(bf16x8, *(const u16x8*)p);
}
__device__ __forceinline__ void gload_lds16(const u16* g, u16* l) {
    __builtin_amdgcn_global_load_lds(
        (const __attribute__((address_space(1))) unsigned int*)g,
        (__attribute__((address_space(3))) unsigned int*)l, 16, 0, 0);
}

// ---------------- fused prologue: trans(W_in) | trans(W_out) | rmsnorm(x) | cwprep ----------------
__device__ void trans_tile(const float* __restrict__ in, u16* __restrict__ out,
                           int K, int N, int n0, int k0)
{
    __shared__ u16 tile[64][66];
    const int tid = threadIdx.x;
#pragma unroll
    for (int r = 0; r < 16; r++) {
        int idx = r * 256 + tid;
        int k = idx >> 6, n = idx & 63;
        float v = (n0 + n < N) ? in[(size_t)(k0 + k) * N + n0 + n] : 0.f;
        tile[n][k] = f2bf(v);
    }
    __syncthreads();
#pragma unroll
    for (int r = 0; r < 16; r++) {
        int idx = r * 256 + tid;
        int n = idx >> 6, k = idx & 63;
        out[(size_t)(n0 + n) * K + k0 + k] = tile[n][k];
    }
}

__global__ __launch_bounds__(256) void prep_kernel(
    const float* __restrict__ W_in, u16* __restrict__ W_inT,
    const float* __restrict__ W_out, u16* __restrict__ W_outT,
    const float* __restrict__ x, const float* __restrict__ nw, u16* __restrict__ xn,
    const float* __restrict__ cw, u16* __restrict__ cwT)
{
    const int blk = blockIdx.x;
    const int tid = threadIdx.x;
    if (blk < 1120) {
        trans_tile(W_in, W_inT, DMODEL, DINPROJ, (blk % 70) * 64, (blk / 70) * 64);
    } else if (blk < 1632) {
        int idx = blk - 1120;
        trans_tile(W_out, W_outT, DINNER, DMODEL, (idx % 16) * 64, (idx / 16) * 64);
    } else if (blk < 5728) {
        const int row = blk - 1632;
        const float* xr = x + (size_t)row * DMODEL;
        float vals[4]; float ss = 0.f;
#pragma unroll
        for (int i = 0; i < 4; i++) {
            int c = tid + i * 256;
            float v = xr[c]; vals[i] = v; ss += v * v;
        }
#pragma unroll
        for (int o = 32; o; o >>= 1) ss += __shfl_xor(ss, o);
        __shared__ float red[4];
        if ((tid & 63) == 0) red[tid >> 6] = ss;
        __syncthreads();
        ss = red[0] + red[1] + red[2] + red[3];
        float sc = rsqrtf(ss / (float)DMODEL + 1e-5f);
#pragma unroll
        for (int i = 0; i < 4; i++) {
            int c = tid + i * 256;
            xn[(size_t)row * DMODEL + c] = f2bf(vals[i] * sc * nw[c]);
        }
    } else {
        for (int idx = tid; idx < 4 * CONVDIM; idx += 256) {
            int k = idx / CONVDIM, c = idx - k * CONVDIM;
            cwT[idx] = f2bf(cw[c * 4 + k]);
        }
    }
}

// ---------------- 128x128 bf16 MFMA GEMM, BK=64, XOR-swizzled, compile-time K ----------------
template<int MODE, int KC>
__global__ __launch_bounds__(256) void gemm128_kernel(
    const u16* __restrict__ A, const u16* __restrict__ BT, void* __restrict__ Cv,
    const float* __restrict__ Res, int Nst, int nbx)
{
    __shared__ u16 As[128 * 64];
    __shared__ u16 Bs[128 * 64];
    const int tid = threadIdx.x;
    const int l = tid & 63, w = tid >> 6;
    const int per = nbx * 8;
    const int grp = blockIdx.x / per, r = blockIdx.x % per;
    const int m0 = (grp * 8 + (r & 7)) * 128;
    const int n0 = (r >> 3) * 128;
    const int ml = l & 15, quad = l >> 4;
    const int wm = (w & 1) * 64, wn = (w >> 1) * 64;
    f32x4 acc[4][4] = {};
    const int srow = l >> 3;
    const int sgx = (l & 7) ^ srow;
    const u16* Ag = A + (size_t)(m0 + w * 8 + srow) * KC + sgx * 8;
    const u16* Bg = BT + (size_t)(n0 + w * 8 + srow) * KC + sgx * 8;
    u16* const As_w = &As[(w * 8) * 64];
    u16* const Bs_w = &Bs[(w * 8) * 64];

#pragma unroll 4
    for (int k0 = 0; k0 < KC; k0 += 64) {
        __syncthreads();
#pragma unroll
        for (int j = 0; j < 4; j++) {
            gload_lds16(Ag + (size_t)(j * 32) * KC + k0, As_w + j * 32 * 64);
            gload_lds16(Bg + (size_t)(j * 32) * KC + k0, Bs_w + j * 32 * 64);
        }
        __syncthreads();
#pragma unroll
        for (int ks4 = 0; ks4 < 2; ks4++) {
            bf16x8 af[4], bfr[4];
#pragma unroll
            for (int i = 0; i < 4; i++)
                af[i] = ldfrag(&As[(wm + i * 16 + ml) * 64 +
                                   (((ks4 * 4 + quad) ^ (ml & 7)) * 8)]);
#pragma unroll
            for (int i = 0; i < 4; i++)
                bfr[i] = ldfrag(&Bs[(wn + i * 16 + ml) * 64 +
                                    (((ks4 * 4 + quad) ^ (ml & 7)) * 8)]);
#pragma unroll
            for (int mt = 0; mt < 4; mt++)
#pragma unroll
                for (int nt = 0; nt < 4; nt++)
                    acc[mt][nt] = __builtin_amdgcn_mfma_f32_16x16x32_bf16(
                        af[mt], bfr[nt], acc[mt][nt], 0, 0, 0);
        }
    }
#pragma unroll
    for (int mt = 0; mt < 4; mt++)
#pragma unroll
        for (int nt = 0; nt < 4; nt++)
#pragma unroll
            for (int rg = 0; rg < 4; rg++) {
                int m = m0 + wm + mt * 16 + quad * 4 + rg;
                int n = n0 + wn + nt * 16 + ml;
                if (n < Nst) {
                    if (MODE == 0)
                        ((u16*)Cv)[(size_t)m * Nst + n] = f2bf(acc[mt][nt][rg]);
                    else
                        ((float*)Cv)[(size_t)m * Nst + n] =
                            acc[mt][nt][rg] + Res[(size_t)m * Nst + n];
                }
            }
}

// ---------------- 128(M)x64(N) bf16 MFMA GEMM, 2D grid (n fastest for A reuse) ----------------
template<int KC>
__global__ __launch_bounds__(256) void gemm128x64_kernel(
    const u16* __restrict__ A, const u16* __restrict__ BT, float* __restrict__ C,
    const float* __restrict__ Res, int Nst)
{
    __shared__ u16 As[128 * 64];
    __shared__ u16 Bs[64 * 64];
    const int tid = threadIdx.x;
    const int l = tid & 63, w = tid >> 6;
    const int m0 = blockIdx.y * 128;
    const int n0 = blockIdx.x * 64;
    const int ml = l & 15, quad = l >> 4;
    const int wm = w * 32;
    f32x4 acc[2][4] = {};
    const int srow = l >> 3;
    const int sgx = (l & 7) ^ srow;
    const u16* Ag = A + (size_t)(m0 + w * 8 + srow) * KC + sgx * 8;
    const u16* Bg = BT + (size_t)(n0 + w * 8 + srow) * KC + sgx * 8;
    u16* const As_w = &As[(w * 8) * 64];
    u16* const Bs_w = &Bs[(w * 8) * 64];

#pragma unroll 4
    for (int k0 = 0; k0 < KC; k0 += 64) {
        __syncthreads();
#pragma unroll
        for (int j = 0; j < 4; j++)
            gload_lds16(Ag + (size_t)(j * 32) * KC + k0, As_w + j * 32 * 64);
#pragma unroll
        for (int j = 0; j < 2; j++)
            gload_lds16(Bg + (size_t)(j * 32) * KC + k0, Bs_w + j * 32 * 64);
        __syncthreads();
#pragma unroll
        for (int ks4 = 0; ks4 < 2; ks4++) {
            bf16x8 af[2], bfr[4];
#pragma unroll
            for (int i = 0; i < 2; i++)
                af[i] = ldfrag(&As[(wm + i * 16 + ml) * 64 +
                                   (((ks4 * 4 + quad) ^ (ml & 7)) * 8)]);
#pragma unroll
            for (int i = 0; i < 4; i++)
                bfr[i] = ldfrag(&Bs[(i * 16 + ml) * 64 +
                                    (((ks4 * 4 + quad) ^ (ml & 7)) * 8)]);
#pragma unroll
            for (int mt = 0; mt < 2; mt++)
#pragma unroll
                for (int nt = 0; nt < 4; nt++)
                    acc[mt][nt] = __builtin_amdgcn_mfma_f32_16x16x32_bf16(
                        af[mt], bfr[nt], acc[mt][nt], 0, 0, 0);
        }
    }
#pragma unroll
    for (int mt = 0; mt < 2; mt++)
#pragma unroll
        for (int nt = 0; nt < 4; nt++)
#pragma unroll
            for (int rg = 0; rg < 4; rg++) {
                int m = m0 + wm + mt * 16 + quad * 4 + rg;
                int n = n0 + nt * 16 + ml;
                C[(size_t)m * Nst + n] = acc[mt][nt][rg] + Res[(size_t)m * Nst + n];
            }
}

// ---------------- depthwise causal conv(4) + bias + SiLU; split X / BC outputs ----------------
#define NGRAN (CONVDIM / 8)   // 288 granules of 8 channels per row
__global__ __launch_bounds__(256) void conv_silu_kernel(
    const u16* __restrict__ zx, const u16* __restrict__ cwT,
    const float* __restrict__ cb, const float* __restrict__ dt_bias,
    u16* __restrict__ Xrow, u16* __restrict__ xbcBC, float* __restrict__ dts)
{
    int idx = blockIdx.x * 256 + threadIdx.x;   // over NROWS*NGRAN
    if (idx < B_SZ * NHEADS * T_SZ) {           // fused softplus(dt)
        int t = idx & (T_SZ - 1);
        int bh = idx >> 11;
        int h = bh & 31, b = bh >> 5;
        float v = bf2f(zx[(size_t)(b * T_SZ + t) * DINPROJ + (DINNER + CONVDIM) + h]) + dt_bias[h];
        float sp = (v > 20.f) ? v : log1pf(expf(v));
        dts[((size_t)bh << 11) + t] = sp;
    }
    int gr = idx % NGRAN;
    int bt = idx / NGRAN;
    int t = bt & (T_SZ - 1);
    int c0 = gr * 8;
    float acc[8];
#pragma unroll
    for (int u = 0; u < 8; u++) acc[u] = cb[c0 + u];
    const u16* base = zx + (size_t)bt * DINPROJ + DINNER + c0;
#pragma unroll
    for (int k = 0; k < 4; k++) {
        int tt = t - 3 + k;
        if (tt >= 0) {
            u16x8 xv = *(const u16x8*)(base + (ptrdiff_t)(k - 3) * DINPROJ);
            u16x8 wv = *(const u16x8*)&cwT[k * CONVDIM + c0];
#pragma unroll
            for (int u = 0; u < 8; u++)
                acc[u] += bf2f(xv[u]) * bf2f(wv[u]);
        }
    }
    u16 res[8];
#pragma unroll
    for (int u = 0; u < 8; u++) {
        float s = acc[u] / (1.f + expf(-acc[u]));
        res[u] = f2bf(s);
    }
    if (c0 < DINNER)
        *(u16x8*)&Xrow[(size_t)bt * DINNER + c0] = *(u16x8*)res;
    else
        *(u16x8*)&xbcBC[(size_t)bt * BCW + (c0 - DINNER)] = *(u16x8*)res;
}

// ---------------- transpose X and B into [channel][t] layouts ----------------
// blk < 2048: X tiles; blk in [2048,2176): B tiles (first 128 ch of xbcBC)
__global__ __launch_bounds__(256) void trans_xbc_kernel(
    const u16* __restrict__ Xrow, const u16* __restrict__ xbcBC,
    u16* __restrict__ xT, u16* __restrict__ BTg)
{
    __shared__ u16 tile[64][66];
    const int blk = blockIdx.x;
    const int tid = threadIdx.x;
    const u16* src; u16* dst; int spitch;
    if (blk < 2048) {
        int b = blk >> 10, r = blk & 1023;
        int ct = r >> 5, tt = r & 31;
        src = Xrow + ((size_t)(b * T_SZ + tt * 64)) * DINNER + ct * 64;
        dst = xT + ((size_t)(b * DINNER + ct * 64)) * T_SZ + tt * 64;
        spitch = DINNER;
    } else {
        int idx = blk - 2048;
        int b = idx >> 6, r = idx & 63;
        int ct = r >> 5, tt = r & 31;
        src = xbcBC + ((size_t)(b * T_SZ + tt * 64)) * BCW + ct * 64;
        dst = BTg + ((size_t)(b * DSTATE + ct * 64)) * T_SZ + tt * 64;
        spitch = BCW;
    }
#pragma unroll
    for (int r = 0; r < 2; r++) {
        int v = r * 256 + tid;          // 0..511
        int i = v >> 3, j8 = (v & 7) * 8;
        u16x8 xv = *(const u16x8*)(src + (size_t)i * spitch + j8);
#pragma unroll
        for (int u = 0; u < 8; u++) tile[j8 + u][i] = xv[u];
    }
    __syncthreads();
#pragma unroll
    for (int r = 0; r < 2; r++) {
        int v = r * 256 + tid;
        int cl = v >> 3, t8 = (v & 7) * 8;
        u16 o[8];
#pragma unroll
        for (int u = 0; u < 8; u++) o[u] = tile[cl][t8 + u];
        *(u16x8*)(dst + (size_t)cl * T_SZ + t8) = *(u16x8*)o;
    }
}

// ---------------- K1: shuffle-scan cumsum + S = Xw^T @ B, fragments from global ----------------
__global__ __launch_bounds__(256) void chunk_state_kernel(
    const u16* __restrict__ xT, const u16* __restrict__ BTg,
    const float* __restrict__ dts_g, const float* __restrict__ A_log,
    float* __restrict__ cs_g, u16* __restrict__ S_bf)
{
    const int g = blockIdx.x;
    const int b = g >> 9, rem = g & 511, c = rem >> 5, h = rem & 31;
    const int tid = threadIdx.x;
    const int lane = tid & 63;
    __shared__ float d2e[128];
    __shared__ float wsum[2];
    const float A = -__expf(A_log[h]);
    float dtv = 0.f, v = 0.f;
    if (tid < 128) {
        dtv = dts_g[(((size_t)(b * 32 + h)) << 11) + (c << 7) + tid];
        v = dtv * A;
    }
#pragma unroll
    for (int off = 1; off < 64; off <<= 1) {
        float n = __shfl_up(v, off);
        if (lane >= off) v += n;
    }
    if (tid < 128 && lane == 63) wsum[tid >> 6] = v;
    __syncthreads();
    if (tid < 128) {
        if (tid >= 64) v += wsum[0];
        float total = wsum[0] + wsum[1];
        cs_g[(((size_t)(b * 32 + h)) << 11) + (c << 7) + tid] = v;
        d2e[tid] = __expf(total - v) * dtv;
    }
    __syncthreads();
    const int wv = tid >> 6, ml = lane & 15, quad = lane >> 4;
    const u16* Ag = xT + ((size_t)(b * DINNER + h * 64 + wv * 16 + ml)) * T_SZ + c * 128 + quad * 8;
    const u16* Bg = BTg + ((size_t)(b * DSTATE + ml)) * T_SZ + c * 128 + quad * 8;
    f32x4 acc[8] = {};
    for (int k0 = 0; k0 < 128; k0 += 32) {
        u16x8 ar = *(const u16x8*)(Ag + k0);
        u16 aw[8];
#pragma unroll
        for (int j = 0; j < 8; j++)
            aw[j] = f2bf(bf2f(ar[j]) * d2e[k0 + quad * 8 + j]);
        bf16x8 af = __builtin_bit_cast(bf16x8, *(u16x8*)aw);
#pragma unroll
        for (int nt = 0; nt < 8; nt++) {
            bf16x8 bf = ldfrag(Bg + (size_t)(nt * 16) * T_SZ + k0);
            acc[nt] = __builtin_amdgcn_mfma_f32_16x16x32_bf16(af, bf, acc[nt], 0, 0, 0);
        }
    }
    const size_t base = (size_t)g * 8192;
#pragma unroll
    for (int nt = 0; nt < 8; nt++) {
#pragma unroll
        for (int rg = 0; rg < 4; rg++) {
            int p = wv * 16 + quad * 4 + rg, n = nt * 16 + ml;
            S_bf[base + p * 128 + n] = f2bf(acc[nt][rg]);
        }
    }
}

// ---------------- K2: inter-chunk recurrence, in-place, prefetched ----------------
__global__ __launch_bounds__(256) void state_pass_kernel(
    const float* __restrict__ cs_g, u16* __restrict__ S_bf)
{
    const int bh = blockIdx.x, b = bh >> 5, h = bh & 31;
    const int tid = threadIdx.x;
    float H[32];
#pragma unroll
    for (int i = 0; i < 32; i++) H[i] = 0.f;
    u16 tvn[32], tv[32];
    {
        size_t slot = ((size_t)((b * NCH) * 32 + h)) * 8192 + tid * 32;
#pragma unroll
        for (int q = 0; q < 4; q++)
            *(u16x8*)&tvn[q * 8] = *(const u16x8*)&S_bf[slot + q * 8];
    }
    for (int c = 0; c < NCH; c++) {
#pragma unroll
        for (int i = 0; i < 32; i++) tv[i] = tvn[i];
        if (c + 1 < NCH) {
            size_t slotn = ((size_t)((b * NCH + c + 1) * 32 + h)) * 8192 + tid * 32;
#pragma unroll
            for (int q = 0; q < 4; q++)
                *(u16x8*)&tvn[q * 8] = *(const u16x8*)&S_bf[slotn + q * 8];
        }
        float decay = __expf(cs_g[(((size_t)(b * 32 + h)) << 11) + (c << 7) + 127]);
        size_t slot = ((size_t)((b * NCH + c) * 32 + h)) * 8192 + tid * 32;
        u16 hw[32];
#pragma unroll
        for (int i = 0; i < 32; i++) hw[i] = f2bf(H[i]);
#pragma unroll
        for (int q = 0; q < 4; q++)
            *(u16x8*)&S_bf[slot + q * 8] = *(const u16x8*)&hw[q * 8];
#pragma unroll
        for (int i = 0; i < 32; i++) H[i] = H[i] * decay + bf2f(tv[i]);
    }
}

// ---------------- K3: chunk output; all operands direct from global; D folded into diag ----------------
__global__ __launch_bounds__(256) void chunk_out_kernel(
    const u16* __restrict__ xbcBC, const u16* __restrict__ xT,
    const float* __restrict__ dts_g, const float* __restrict__ cs_g,
    const u16* __restrict__ H_bf, const float* __restrict__ Dv, u16* __restrict__ yraw)
{
    const int g = blockIdx.x;
    const int b = g >> 9, rem = g & 511, c = rem >> 5, h = rem & 31;
    const int tid = threadIdx.x;
    __shared__ u16 Gs[128][40];
    __shared__ float cs_l[128], P_l[128], dt_l[128];
    const size_t bcbase = ((size_t)(b * T_SZ + c * L_CH)) * BCW;
    const u16* Cg = xbcBC + bcbase + 128;     // [t][n] pitch BCW
    const u16* Bg = xbcBC + bcbase;           // [j][n] pitch BCW
    const u16* Hg = H_bf + (size_t)g * 8192;  // [p][n] pitch 128
    const u16* Xg = xT + ((size_t)(b * DINNER + h * 64)) * T_SZ + c * 128; // row p: +p*T_SZ
    const float Dh = Dv[h];
    if (tid < 128) {
        float cs = cs_g[(((size_t)(b * 32 + h)) << 11) + (c << 7) + tid];
        cs_l[tid] = cs; P_l[tid] = __expf(cs);
        dt_l[tid] = dts_g[(((size_t)(b * 32 + h)) << 11) + (c << 7) + tid];
    }
    __syncthreads();
    const int lane = tid & 63, wv = tid >> 6, ml = lane & 15, quad = lane >> 4;
    const int trow = wv * 32;
    f32x4 accY[2][4] = {};
    for (int k0 = 0; k0 < 128; k0 += 32) {
        bf16x8 af0 = ldfrag(Cg + (size_t)(trow + ml) * BCW + k0 + quad * 8);
        bf16x8 af1 = ldfrag(Cg + (size_t)(trow + 16 + ml) * BCW + k0 + quad * 8);
#pragma unroll
        for (int pt = 0; pt < 4; pt++) {
            bf16x8 bf = ldfrag(Hg + (pt * 16 + ml) * 128 + k0 + quad * 8);
            accY[0][pt] = __builtin_amdgcn_mfma_f32_16x16x32_bf16(af0, bf, accY[0][pt], 0, 0, 0);
            accY[1][pt] = __builtin_amdgcn_mfma_f32_16x16x32_bf16(af1, bf, accY[1][pt], 0, 0, 0);
        }
    }
#pragma unroll
    for (int mt = 0; mt < 2; mt++) {
#pragma unroll
        for (int rg = 0; rg < 4; rg++) {
            float pp = P_l[trow + mt * 16 + quad * 4 + rg];
#pragma unroll
            for (int pt = 0; pt < 4; pt++) accY[mt][pt][rg] *= pp;
        }
    }
    for (int js = 0; js < 4; js++) {
        const int j0 = js * 32;
        f32x4 Ga[2][2] = {};
        for (int k0 = 0; k0 < 128; k0 += 32) {
            bf16x8 af0 = ldfrag(Cg + (size_t)(trow + ml) * BCW + k0 + quad * 8);
            bf16x8 af1 = ldfrag(Cg + (size_t)(trow + 16 + ml) * BCW + k0 + quad * 8);
            bf16x8 bf0 = ldfrag(Bg + (size_t)(j0 + ml) * BCW + k0 + quad * 8);
            bf16x8 bf1 = ldfrag(Bg + (size_t)(j0 + 16 + ml) * BCW + k0 + quad * 8);
            Ga[0][0] = __builtin_amdgcn_mfma_f32_16x16x32_bf16(af0, bf0, Ga[0][0], 0, 0, 0);
            Ga[0][1] = __builtin_amdgcn_mfma_f32_16x16x32_bf16(af0, bf1, Ga[0][1], 0, 0, 0);
            Ga[1][0] = __builtin_amdgcn_mfma_f32_16x16x32_bf16(af1, bf0, Ga[1][0], 0, 0, 0);
            Ga[1][1] = __builtin_amdgcn_mfma_f32_16x16x32_bf16(af1, bf1, Ga[1][1], 0, 0, 0);
        }
#pragma unroll
        for (int mt = 0; mt < 2; mt++) {
#pragma unroll
            for (int jt = 0; jt < 2; jt++) {
#pragma unroll
                for (int rg = 0; rg < 4; rg++) {
                    int t = trow + mt * 16 + quad * 4 + rg;
                    int j = j0 + jt * 16 + ml;
                    float val = 0.f;
                    if (t >= j) val = Ga[mt][jt][rg] * __expf(cs_l[t] - cs_l[j]) * dt_l[j];
                    if (t == j) val += Dh;          // D*x folded into diagonal
                    Gs[t][jt * 16 + ml] = f2bf(val);
                }
            }
        }
#pragma unroll
        for (int mt = 0; mt < 2; mt++) {
            bf16x8 af = ldfrag(&Gs[trow + mt * 16 + ml][quad * 8]);
#pragma unroll
            for (int pt = 0; pt < 4; pt++) {
                bf16x8 bf = ldfrag(Xg + (size_t)(pt * 16 + ml) * T_SZ + j0 + quad * 8);
                accY[mt][pt] = __builtin_amdgcn_mfma_f32_16x16x32_bf16(af, bf, accY[mt][pt], 0, 0, 0);
            }
        }
    }
    const size_t ybase = ((size_t)(b * T_SZ + c * L_CH)) * DINNER;
#pragma unroll
    for (int mt = 0; mt < 2; mt++) {
#pragma unroll
        for (int pt = 0; pt < 4; pt++) {
#pragma unroll
            for (int rg = 0; rg < 4; rg++) {
                int t = trow + mt * 16 + quad * 4 + rg;
                int p = pt * 16 + ml;
                yraw[ybase + (size_t)t * DINNER + h * 64 + p] = f2bf(accY[mt][pt][rg]);
            }
        }
    }
}

// ---------------- y = rmsnorm(yraw * silu(z)) * gnorm_w (D=2048) ----------------
__global__ __launch_bounds__(256) void postnorm_kernel(
    const u16* __restrict__ yraw, const u16* __restrict__ zx,
    const float* __restrict__ gw, u16* __restrict__ out)
{
    const int row = blockIdx.x;
    const u16* yr = yraw + (size_t)row * DINNER;
    const u16* zr = zx + (size_t)row * DINPROJ;
    float vals[8]; float ss = 0.f;
#pragma unroll
    for (int i = 0; i < 8; i++) {
        int c = threadIdx.x + i * 256;
        float y = bf2f(yr[c]);
        float z = bf2f(zr[c]);
        float s = z / (1.f + expf(-z));
        float t = y * s; vals[i] = t; ss += t * t;
    }
#pragma unroll
    for (int o = 32; o; o >>= 1) ss += __shfl_xor(ss, o);
    __shared__ float red[4];
    if ((threadIdx.x & 63) == 0) red[threadIdx.x >> 6] = ss;
    __syncthreads();
    ss = red[0] + red[1] + red[2] + red[3];
    float sc = rsqrtf(ss / (float)DINNER + 1e-5f);
#pragma unroll
    for (int i = 0; i < 8; i++) {
        int c = threadIdx.x + i * 256;
        out[(size_t)row * DINNER + c] = f2bf(vals[i] * sc * gw[c]);
    }
}

extern "C" void kernel_launch(void* const* d_in, const int* in_sizes, int n_in,
                              void* d_out, int out_size, void* d_ws, size_t ws_size,
                              hipStream_t stream) {
    const float* x       = (const float*)d_in[0];
    const float* W_in    = (const float*)d_in[1];
    const float* conv_w  = (const float*)d_in[2];
    const float* conv_b  = (const float*)d_in[3];
    const float* dt_bias = (const float*)d_in[4];
    const float* A_log   = (const float*)d_in[5];
    const float* Dv      = (const float*)d_in[6];
    const float* norm_w  = (const float*)d_in[7];
    const float* gnorm_w = (const float*)d_in[8];
    const float* W_out   = (const float*)d_in[9];
    float* out = (float*)d_out;

    char* ws = (char*)d_ws;
    u16*   xn    = (u16*)(ws);                  // [0, 8.39M); later S_bf
    u16*   W_inT = (u16*)(ws + 8388608);        // 9.18M, dead after GEMM1
    u16*   S_bf  = (u16*)(ws);                  // 16.78M (after GEMM1)
    float* cs_g  = (float*)(ws + 16777216);     // 0.52M
    u16*   zx    = (u16*)(ws + 17563648);       // 35.91M
    u16*   Xrow  = (u16*)(ws + 53477376);       // 16.78M (dead after trans; yraw aliases)
    u16*   yraw  = Xrow;
    u16*   xT    = (u16*)(ws + 70254592);       // 16.78M
    u16*   xbcBC = (u16*)(ws + 87031808);       //  2.10M
    u16*   BTg   = (u16*)(ws + 89128960);       //  1.05M
    float* dts   = (float*)(ws + 90177536);     //  0.52M
    u16*   cwT   = (u16*)(ws + 90701824);       //  0.02M
    u16*   W_outT= (u16*)(ws + 90720256);       //  4.19M (end 94,914,560)
    u16*   ynorm = yraw;                        // postnorm in-place safe

    prep_kernel<<<5729, 256, 0, stream>>>(
        W_in, W_inT, W_out, W_outT, x, norm_w, xn, conv_w, cwT);
    gemm128_kernel<0, DMODEL><<<(DINPROJ_P / 128) * (NROWS / 128), 256, 0, stream>>>(
        xn, W_inT, zx, nullptr, DINPROJ, DINPROJ_P / 128);
    conv_silu_kernel<<<(NROWS * NGRAN) / 256, 256, 0, stream>>>(
        zx, cwT, conv_b, dt_bias, Xrow, xbcBC, dts);
    trans_xbc_kernel<<<2176, 256, 0, stream>>>(Xrow, xbcBC, xT, BTg);
    chunk_state_kernel<<<B_SZ * NCH * NHEADS, 256, 0, stream>>>(
        xT, BTg, dts, A_log, cs_g, S_bf);
    state_pass_kernel<<<B_SZ * NHEADS, 256, 0, stream>>>(cs_g, S_bf);
    chunk_out_kernel<<<B_SZ * NCH * NHEADS, 256, 0, stream>>>(
        xbcBC, xT, dts, cs_g, S_bf, Dv, yraw);
    postnorm_kernel<<<NROWS, 256, 0, stream>>>(yraw, zx, gnorm_w, ynorm);
    gemm128x64_kernel<DINNER><<<dim3(DMODEL / 64, NROWS / 128), 256, 0, stream>>>(
        ynorm, W_outT, out, x, DMODEL);
}